// Round 11
// baseline (197.512 us; speedup 1.0000x reference)
//
#include <hip/hip_runtime.h>
#include <hip/hip_bf16.h>
#include <stdint.h>
#include <stddef.h>

typedef __attribute__((ext_vector_type(4))) float f32x4;
typedef __attribute__((ext_vector_type(8))) short s16x8;

#define B_    8
#define L_    8192
#define N_    256
#define DOUT_ 256
#define M_    8192      // complex FFT length = n_fft/2
#define GSTRIDE 8200    // complex row stride for U/G (8193 used)
#define RC    0.70710678118654752f
#define C8    0.92387953251128675613f   // cos(pi/8)
#define S8    0.38268343236508977173f   // sin(pi/8)

__device__ __forceinline__ unsigned short f2bf(float f) {
  unsigned int x = __float_as_uint(f);
  x += 0x7fff + ((x >> 16) & 1);   // RNE
  return (unsigned short)(x >> 16);
}

__device__ __forceinline__ float2 cmul(float2 a, float2 b) {
  return make_float2(a.x * b.x - a.y * b.y, a.x * b.y + a.y * b.x);
}
__device__ __forceinline__ float2 cadd(float2 a, float2 b) { return make_float2(a.x + b.x, a.y + b.y); }
__device__ __forceinline__ float2 csub(float2 a, float2 b) { return make_float2(a.x - b.x, a.y - b.y); }

// LDS index swizzle, bit 0 preserved (R9 lesson: fused (m,m+1) float4 pair reads
// need even-aligned pairs). Folds bits 4..12 into bits 1..3. Bijective.
__device__ __forceinline__ int phi(int i) {
  return i ^ ((((i >> 4) ^ (i >> 7) ^ (i >> 10)) & 7) << 1);
}
__device__ __forceinline__ int rev13(int i) { return (int)(__brev((unsigned)i) >> 19); }

// w is the FORWARD twiddle; INV applies conjugate
template<bool INV> __device__ __forceinline__ float2 twmul(float2 x, float2 w) {
  return INV ? make_float2(x.x * w.x + x.y * w.y, x.y * w.x - x.x * w.y)
             : make_float2(x.x * w.x - x.y * w.y, x.x * w.y + x.y * w.x);
}
template<bool INV> __device__ __forceinline__ float2 mul_mi(float2 x) {   // *(−i) fwd
  return INV ? make_float2(-x.y, x.x) : make_float2(x.y, -x.x);
}
template<bool INV> __device__ __forceinline__ float2 mul_w8(float2 x) {   // *e^{−iπ/4} fwd
  return INV ? make_float2(RC * (x.x - x.y), RC * (x.x + x.y))
             : make_float2(RC * (x.x + x.y), RC * (x.y - x.x));
}
template<bool INV> __device__ __forceinline__ float2 mul_w83(float2 x) {  // *e^{−3iπ/4} fwd
  return INV ? make_float2(-RC * (x.x + x.y), RC * (x.x - x.y))
             : make_float2(RC * (x.y - x.x), -RC * (x.x + x.y));
}

// ---- radix-16 butterfly (4 DIF stages) in registers; R10-proven twiddle algebra ----
template<bool INV>
__device__ __forceinline__ void r16(float2* a, float2 wA, float2 wB, float2 wC, float2 wD) {
  float2 b[16];
#pragma unroll
  for (int k = 0; k < 8; ++k) {
    b[k] = cadd(a[k], a[k + 8]);
    float2 t = twmul<INV>(csub(a[k], a[k + 8]), wA);
    if (k == 1) t = twmul<INV>(t, make_float2(C8, -S8));
    else if (k == 2) t = mul_w8<INV>(t);
    else if (k == 3) t = twmul<INV>(t, make_float2(S8, -C8));
    else if (k == 4) t = mul_mi<INV>(t);
    else if (k == 5) t = twmul<INV>(t, make_float2(-S8, -C8));
    else if (k == 6) t = mul_w83<INV>(t);
    else if (k == 7) t = twmul<INV>(t, make_float2(-C8, -S8));
    b[k + 8] = t;
  }
  float2 c[16];
#pragma unroll
  for (int blk = 0; blk < 16; blk += 8)
#pragma unroll
    for (int k = 0; k < 4; ++k) {
      c[blk + k] = cadd(b[blk + k], b[blk + k + 4]);
      float2 t = twmul<INV>(csub(b[blk + k], b[blk + k + 4]), wB);
      if (k == 1) t = mul_w8<INV>(t);
      else if (k == 2) t = mul_mi<INV>(t);
      else if (k == 3) t = mul_w83<INV>(t);
      c[blk + k + 4] = t;
    }
  float2 d[16];
#pragma unroll
  for (int blk = 0; blk < 16; blk += 4)
#pragma unroll
    for (int k = 0; k < 2; ++k) {
      d[blk + k] = cadd(c[blk + k], c[blk + k + 2]);
      float2 t = twmul<INV>(csub(c[blk + k], c[blk + k + 2]), wC);
      if (k == 1) t = mul_mi<INV>(t);
      d[blk + k + 2] = t;
    }
#pragma unroll
  for (int blk = 0; blk < 16; blk += 2) {
    a[blk]     = cadd(d[blk], d[blk + 1]);
    a[blk + 1] = twmul<INV>(csub(d[blk], d[blk + 1]), wD);
  }
}

// preload the 12 per-pass base twiddles (pass i: p_i = tid & (T_i-1), T = 512,32,2)
__device__ __forceinline__ void preload_tw(const float2* __restrict__ tw, int tid, float2* twp) {
  const int p0 = tid, p1 = tid & 31, p2 = tid & 1;
  twp[0] = tw[p0 << 1];  twp[1] = tw[p0 << 2];  twp[2]  = tw[p0 << 3];  twp[3]  = tw[p0 << 4];
  twp[4] = tw[p1 << 5];  twp[5] = tw[p1 << 6];  twp[6]  = tw[p1 << 7];  twp[7]  = tw[p1 << 8];
  twp[8] = tw[p2 << 9];  twp[9] = tw[p2 << 10]; twp[10] = tw[p2 << 11]; twp[11] = tw[p2 << 12];
}

// single-job pass (k_ffwd)
#define FFT_PASS(INV, SH, BASE, W0, W1, W2, W3) do { \
    const int base_ = (BASE); \
    float2 a_[16]; \
    _Pragma("unroll") \
    for (int k = 0; k < 16; ++k) a_[k] = zc[phi(base_ + (k << (SH)))]; \
    r16<INV>(a_, W0, W1, W2, W3); \
    _Pragma("unroll") \
    for (int k = 0; k < 16; ++k) zc[phi(base_ + (k << (SH)))] = a_[k]; \
  } while (0)

template<bool INV>
__device__ __forceinline__ void fft12(float2* zc, int tid, const float2* twp) {
  FFT_PASS(INV, 9, tid, twp[0], twp[1], twp[2], twp[3]);
  __syncthreads();
  FFT_PASS(INV, 5, ((tid >> 5) << 9) + (tid & 31), twp[4], twp[5], twp[6], twp[7]);
  __syncthreads();
  FFT_PASS(INV, 1, ((tid >> 1) << 5) + (tid & 1), twp[8], twp[9], twp[10], twp[11]);
  __syncthreads();
}

// two-job pass: shared swizzled addresses, two independent r16 streams per barrier
#define FFT_PASS2(INV, SH, BASE, W0, W1, W2, W3) do { \
    const int base_ = (BASE); \
    int ix_[16]; \
    _Pragma("unroll") \
    for (int k = 0; k < 16; ++k) ix_[k] = phi(base_ + (k << (SH))); \
    float2 aA_[16], aB_[16]; \
    _Pragma("unroll") \
    for (int k = 0; k < 16; ++k) aA_[k] = zA[ix_[k]]; \
    _Pragma("unroll") \
    for (int k = 0; k < 16; ++k) aB_[k] = zB[ix_[k]]; \
    r16<INV>(aA_, W0, W1, W2, W3); \
    _Pragma("unroll") \
    for (int k = 0; k < 16; ++k) zA[ix_[k]] = aA_[k]; \
    r16<INV>(aB_, W0, W1, W2, W3); \
    _Pragma("unroll") \
    for (int k = 0; k < 16; ++k) zB[ix_[k]] = aB_[k]; \
  } while (0)

// ---- kernel 1: twiddle LUT tw[k] = e^{-2*pi*i*k/16384}, k=0..8191 ----
__global__ void k_tw(float2* __restrict__ tw) {
  int k = blockIdx.x * 256 + threadIdx.x;   // 8192 threads
  float a = (float)k * 3.8349519697141029e-4f;   // 2*pi/16384
  tw[k] = make_float2(__cosf(a), -__sinf(a));
}

// ---- kernel 2: gT[o][i] = sum_n W[o][n]*h[i][n], bf16 MFMA ----
__global__ void k_gt(const float* __restrict__ W, const float* __restrict__ h,
                     unsigned short* __restrict__ gT) {
  int gid  = blockIdx.x * 256 + threadIdx.x;
  int lane = gid & 63;
  int wid  = gid >> 6;
  int o_t  = wid >> 7;
  int i_t  = wid & 127;
  int o0 = o_t * 16, i0 = i_t * 64;
  int ln = lane & 15, hi = lane >> 4;
  f32x4 acc[4] = {};
#pragma unroll
  for (int k0 = 0; k0 < N_; k0 += 32) {
    const float* wp = W + (o0 + ln) * N_ + k0 + 8 * hi;
    float4 w0 = *(const float4*)wp;
    float4 w1 = *(const float4*)(wp + 4);
    s16x8 a;
    a[0] = (short)f2bf(w0.x); a[1] = (short)f2bf(w0.y);
    a[2] = (short)f2bf(w0.z); a[3] = (short)f2bf(w0.w);
    a[4] = (short)f2bf(w1.x); a[5] = (short)f2bf(w1.y);
    a[6] = (short)f2bf(w1.z); a[7] = (short)f2bf(w1.w);
#pragma unroll
    for (int ns = 0; ns < 4; ++ns) {
      const float* hp = h + (size_t)(i0 + 16 * ns + ln) * N_ + k0 + 8 * hi;
      float4 h0 = *(const float4*)hp;
      float4 h1 = *(const float4*)(hp + 4);
      s16x8 bb;
      bb[0] = (short)f2bf(h0.x); bb[1] = (short)f2bf(h0.y);
      bb[2] = (short)f2bf(h0.z); bb[3] = (short)f2bf(h0.w);
      bb[4] = (short)f2bf(h1.x); bb[5] = (short)f2bf(h1.y);
      bb[6] = (short)f2bf(h1.z); bb[7] = (short)f2bf(h1.w);
      acc[ns] = __builtin_amdgcn_mfma_f32_16x16x32_bf16(a, bb, acc[ns], 0, 0, 0);
    }
  }
#pragma unroll
  for (int ns = 0; ns < 4; ++ns)
#pragma unroll
    for (int q = 0; q < 4; ++q)
      gT[(size_t)(o0 + 4 * hi + q) * L_ + i0 + 16 * ns + ln] = f2bf(acc[ns][q]);
}

// ---- kernel 3: forward rffts; G rows pre-scaled by 1/8192 (folds irfft norm) ----
__global__ __launch_bounds__(512, 4) void k_ffwd(const float* __restrict__ u,
                                                 const unsigned short* __restrict__ gT,
                                                 const float2* __restrict__ tw,
                                                 float2* __restrict__ U,
                                                 float2* __restrict__ G) {
  __shared__ __align__(16) float2 zc[M_];   // 64 KB
  const int wg = blockIdx.x;
  const int tid = threadIdx.x;
  float2 twp[12];
  preload_tw(tw, tid, twp);

  if (wg < 8) {
    const float2* src = (const float2*)(u + wg * L_);
#pragma unroll 4
    for (int kp = 0; kp < 16; ++kp) {
      int t = tid + 512 * kp;
      zc[phi(t)] = (t < 4096) ? src[t] : make_float2(0.f, 0.f);
    }
  } else {
    const unsigned int* src = (const unsigned int*)(gT + (size_t)(wg - 8) * L_);
#pragma unroll 4
    for (int kp = 0; kp < 16; ++kp) {
      int t = tid + 512 * kp;
      float2 v = make_float2(0.f, 0.f);
      if (t < 4096) {
        unsigned int pr = src[t];   // 2 bf16
        v.x = __uint_as_float(pr << 16);
        v.y = __uint_as_float(pr & 0xffff0000u);
      }
      zc[phi(t)] = v;
    }
  }
  __syncthreads();

  fft12<false>(zc, tid, twp);

  // fused stage 12 + rfft unpack; scale G rows by 1/8192 (irfft normalization)
  const float sc = (wg < 8) ? 1.0f : (1.0f / 8192.0f);
  float2* dst = (wg < 8) ? (U + (size_t)wg * GSTRIDE) : (G + (size_t)(wg - 8) * GSTRIDE);
#pragma unroll 4
  for (int kp = 0; kp < 16; ++kp) {
    int k = tid + 512 * kp;
    int m1 = rev13(k);
    int m2 = rev13((M_ - k) & (M_ - 1));
    float4 v1 = *(const float4*)(zc + phi(m1 & ~1));
    float4 v2 = *(const float4*)(zc + phi(m2 & ~1));
    float2 zk  = (m1 & 1) ? make_float2(v1.x - v1.z, v1.y - v1.w)
                          : make_float2(v1.x + v1.z, v1.y + v1.w);
    float2 zmk = (m2 & 1) ? make_float2(v2.x - v2.z, v2.y - v2.w)
                          : make_float2(v2.x + v2.z, v2.y + v2.w);
    float2 E = make_float2(0.5f * (zk.x + zmk.x), 0.5f * (zk.y - zmk.y));
    float2 O = make_float2(0.5f * (zk.y + zmk.y), 0.5f * (zmk.x - zk.x));
    float2 w = tw[k];
    float2 X = cmul(w, O);
    dst[k] = make_float2((E.x + X.x) * sc, (E.y + X.y) * sc);
  }
  if (tid == 0) {
    float4 v = *(const float4*)zc;          // w[0], w[1]  (phi(0)=0, phi(1)=1)
    float2 z0 = make_float2(v.x + v.z, v.y + v.w);
    dst[M_] = make_float2((z0.x - z0.y) * sc, 0.f);   // X[8192]
  }
}

// ---- kernel 4: TWO convolutions per wg: (b, o0=2s) and (b, o0+1) ----
// ILP interleave: two 64KB LDS arrays, shared swizzled addresses, two r16 streams
// per barrier; paired float2 output stores (adjacent o). XCD remap keeps one b
// per XCD with ascending o (R7-proven store merge).
__global__ __launch_bounds__(512, 2) void k_conv(const float2* __restrict__ U,
                                                 const float2* __restrict__ G,
                                                 const float2* __restrict__ tw,
                                                 float* __restrict__ out) {
  __shared__ __align__(16) float2 zA[M_];   // 64 KB
  __shared__ __align__(16) float2 zB[M_];   // 64 KB
  const int bid = blockIdx.x;    // 1024
  const int b = bid & 7;         // one batch per XCD
  const int o0 = (bid >> 3) * 2; // 0,2,..,254 ascending within XCD
  const int tid = threadIdx.x;
  const float2* Ub = U + (size_t)b * GSTRIDE;
  const float2* GA = G + (size_t)o0 * GSTRIDE;
  const float2* GB = GA + GSTRIDE;
  float2 twp[12];
  preload_tw(tw, tid, twp);

  // pack both jobs: Z[k] = E + i*O', pair (k, M-k) processed together
#pragma unroll 2
  for (int kp = 0; kp < 8; ++kp) {
    int k = tid + 512 * kp;            // 0..4095
    float2 Uk = Ub[k];
    float2 YA = cmul(Uk, GA[k]);
    float2 YB = cmul(Uk, GB[k]);
    if (k == 0) {
      float2 Um = Ub[M_];
      float2 YAm = cmul(Um, GA[M_]);
      float2 YBm = cmul(Um, GB[M_]);
      float2 EA = make_float2(0.5f * (YA.x + YAm.x), 0.5f * (YA.y - YAm.y));
      float2 DA = make_float2(0.5f * (YA.x - YAm.x), 0.5f * (YA.y + YAm.y));
      float2 EB = make_float2(0.5f * (YB.x + YBm.x), 0.5f * (YB.y - YBm.y));
      float2 DB = make_float2(0.5f * (YB.x - YBm.x), 0.5f * (YB.y + YBm.y));
      zA[0] = make_float2(EA.x - DA.y, EA.y + DA.x);   // phi(0)=0
      zB[0] = make_float2(EB.x - DB.y, EB.y + DB.x);
      float2 U4 = Ub[4096];
      float2 YA4 = cmul(U4, GA[4096]);
      float2 YB4 = cmul(U4, GB[4096]);
      zA[phi(4096)] = make_float2(YA4.x, -YA4.y);      // Z[4096] = conj(Y[4096])
      zB[phi(4096)] = make_float2(YB4.x, -YB4.y);
    } else {
      float2 Umk = Ub[M_ - k];
      float2 YAm = cmul(Umk, GA[M_ - k]);
      float2 YBm = cmul(Umk, GB[M_ - k]);
      float2 w = tw[k];                // O' = D * conj(tw[k])
      float2 EA = make_float2(0.5f * (YA.x + YAm.x), 0.5f * (YA.y - YAm.y));
      float2 DA = make_float2(0.5f * (YA.x - YAm.x), 0.5f * (YA.y + YAm.y));
      float2 OA = make_float2(DA.x * w.x + DA.y * w.y, -DA.x * w.y + DA.y * w.x);
      zA[phi(k)]      = make_float2(EA.x - OA.y,  EA.y + OA.x);
      zA[phi(M_ - k)] = make_float2(EA.x + OA.y, -EA.y + OA.x);
      float2 EB = make_float2(0.5f * (YB.x + YBm.x), 0.5f * (YB.y - YBm.y));
      float2 DB = make_float2(0.5f * (YB.x - YBm.x), 0.5f * (YB.y + YBm.y));
      float2 OB = make_float2(DB.x * w.x + DB.y * w.y, -DB.x * w.y + DB.y * w.x);
      zB[phi(k)]      = make_float2(EB.x - OB.y,  EB.y + OB.x);
      zB[phi(M_ - k)] = make_float2(EB.x + OB.y, -EB.y + OB.x);
    }
  }
  __syncthreads();

  // stages 0..11 of icfft on both jobs (3 barriers total, shared addresses)
  FFT_PASS2(true, 9, tid, twp[0], twp[1], twp[2], twp[3]);
  __syncthreads();
  FFT_PASS2(true, 5, ((tid >> 5) << 9) + (tid & 31), twp[4], twp[5], twp[6], twp[7]);
  __syncthreads();
  FFT_PASS2(true, 1, ((tid >> 1) << 5) + (tid & 1), twp[8], twp[9], twp[10], twp[11]);
  __syncthreads();

  // fused stage 12: t<4096 <=> even bitrev m -> SUM outputs only.
  // out[l][o0], out[l][o0+1] adjacent -> one aligned float2 store per l.
  float* ob = out + (size_t)b * (L_ * DOUT_) + o0;
#pragma unroll 2
  for (int kp = 0; kp < 8; ++kp) {
    int t = tid + 512 * kp;            // 0..4095
    int m = rev13(t);                  // even
    int sm = phi(m);
    float4 vA = *(const float4*)(zA + sm);   // (w[m], w[m+1]) aligned pair
    float4 vB = *(const float4*)(zB + sm);
    *(float2*)(ob + (size_t)(2 * t) * DOUT_)     = make_float2(vA.x + vA.z, vB.x + vB.z);
    *(float2*)(ob + (size_t)(2 * t + 1) * DOUT_) = make_float2(vA.y + vA.w, vB.y + vB.w);
  }
}

extern "C" void kernel_launch(void* const* d_in, const int* in_sizes, int n_in,
                              void* d_out, int out_size, void* d_ws, size_t ws_size,
                              hipStream_t stream) {
  const float* u = (const float*)d_in[0];   // [8, 8192, 1]
  const float* h = (const float*)d_in[1];   // [8192, 256]
  const float* W = (const float*)d_in[2];   // [256, 256]
  float* out = (float*)d_out;               // [8, 8192, 256]

  char* ws = (char*)d_ws;
  unsigned short* gT = (unsigned short*)ws;                       // 4 MB bf16 [256][8192]
  float2* tw = (float2*)(ws + (size_t)4 * 1024 * 1024);           // 64 KB
  float2* U  = (float2*)(ws + (size_t)4 * 1024 * 1024 + 65536);   // 512.5 KB
  float2* G  = (float2*)(ws + (size_t)4 * 1024 * 1024 + 65536 + 524800);  // 16.0 MB

  k_tw<<<32, 256, 0, stream>>>(tw);
  k_gt<<<512, 256, 0, stream>>>(W, h, gT);
  k_ffwd<<<264, 512, 0, stream>>>(u, gT, tw, U, G);
  k_conv<<<1024, 512, 0, stream>>>(U, G, tw, out);
}